// Round 9
// baseline (611.920 us; speedup 1.0000x reference)
//
#include <hip/hip_runtime.h>
#include <stdint.h>

#define KCAPS 10
#define OC    16
#define IC    256
#define HWSZ  36
#define PRIM  72
#define PD    8
#define EDIM  16

typedef short bf16x8 __attribute__((ext_vector_type(8)));
typedef float f32x4  __attribute__((ext_vector_type(4)));

// persistent prepped weights (recomputed every launch -> deterministic)
__device__ unsigned short g_whi[KCAPS * OC * IC];
__device__ unsigned short g_wlo[KCAPS * OC * IC];
__device__ float          g_wtsT[KCAPS * PRIM * EDIM * PD];   // [k][p][e][d]

// LDS map (44352 B):
//   [0, 19008)      xsh u32[36][132]  (bf16 [36][264])
//   [19008, 38016)  xsl u32[36][132]
//   [38016, 44352)  slack: GEMM A-fragment reads for discarded D-rows 36..47
//                   over-run xsl (garbage, in-bounds, results discarded)
//   post-GEMM overlay (xs dead after barrier #2):
//   f32 [0, 5760)       caps [10][576]
//   f32 [5760, 8064)    u89  [2][72][16]
//   f32 [8064, 8784)    b_s  [720]
//   f32 [8784, 9504)    c_s  [720]
#define SMEM_BYTES 44352

__device__ __forceinline__ void bf_split(float v, unsigned short& hb, unsigned short& lb) {
    __bf16 h = (__bf16)v;
    hb = __builtin_bit_cast(unsigned short, h);
    __bf16 l = (__bf16)(v - (float)h);
    lb = __builtin_bit_cast(unsigned short, l);
}

__device__ __forceinline__ f32x4 mfma16(bf16x8 a, bf16x8 b, f32x4 c) {
    return __builtin_amdgcn_mfma_f32_16x16x32_bf16(a, b, c, 0, 0, 0);
}

__global__ __launch_bounds__(256)
void prep_kernel(const float* __restrict__ w, const float* __restrict__ wts) {
    int i = blockIdx.x * 256 + threadIdx.x;
    if (i < KCAPS * OC * IC) {
        unsigned short hb, lb;
        bf_split(w[i], hb, lb);
        g_whi[i] = hb;
        g_wlo[i] = lb;
    }
    if (i < KCAPS * PRIM * EDIM * PD) {           // 92160: [kp][e][d] <- [kp][d][e]
        int d = i & 7, e = (i >> 3) & 15, kp = i >> 7;
        g_wtsT[i] = wts[(size_t)kp * 128 + d * 16 + e];
    }
}

__global__ __launch_bounds__(512, 6)
void caps_512(const float* __restrict__ x, const float* __restrict__ conv_b,
              const float* __restrict__ wts, float* __restrict__ out) {
    extern __shared__ char smem[];
    uint32_t* xsh = (uint32_t*)smem;              // [36][132]
    uint32_t* xsl = xsh + 36 * 132;               // [36][132] (+slack beyond)
    const short* xshS = (const short*)xsh;
    const short* xslS = (const short*)xsl;
    float* sm_f   = (float*)smem;
    float* caps_s = sm_f;                         // [10][576]
    float* u89    = sm_f + 5760;                  // [2][72][16]
    float* b_s    = sm_f + 8064;                  // [720]
    float* c_s    = sm_f + 8784;                  // [720]

    const int t  = threadIdx.x;
    const int bb = blockIdx.x;
    const int wv = t >> 6;            // wave 0..7 owns capsule wv; waves 0,1 also 8,9
    const int ln = t & 63;
    const int row = ln & 15;          // GEMM: tile row | routing: e
    const int g   = ln >> 4;          // GEMM: k-group  | routing: pr
    const int e   = row;
    const int pr  = g;
    const bool dual = (wv < 2);
    const int kB = 8 + wv;

    // ---- phase 0: stage x transposed -> bf16 hi/lo [36 hw][264 c]
    {
        const float4* x4 = (const float4*)(x + (size_t)bb * (IC * HWSZ));
        for (int task = t; task < 1152; task += 512) {   // 128 c-pairs x 9 hw-quads
            int cp = task / 9, hq = task - cp * 9;
            float4 va = x4[(2 * cp) * 9 + hq];
            float4 vb = x4[(2 * cp + 1) * 9 + hq];
            int base = (4 * hq) * 132 + cp;
            unsigned short ha, la, hb, lb;
            bf_split(va.x, ha, la); bf_split(vb.x, hb, lb);
            xsh[base]       = (uint32_t)ha | ((uint32_t)hb << 16);
            xsl[base]       = (uint32_t)la | ((uint32_t)lb << 16);
            bf_split(va.y, ha, la); bf_split(vb.y, hb, lb);
            xsh[base + 132] = (uint32_t)ha | ((uint32_t)hb << 16);
            xsl[base + 132] = (uint32_t)la | ((uint32_t)lb << 16);
            bf_split(va.z, ha, la); bf_split(vb.z, hb, lb);
            xsh[base + 264] = (uint32_t)ha | ((uint32_t)hb << 16);
            xsl[base + 264] = (uint32_t)la | ((uint32_t)lb << 16);
            bf_split(va.w, ha, la); bf_split(vb.w, hb, lb);
            xsh[base + 396] = (uint32_t)ha | ((uint32_t)hb << 16);
            xsl[base + 396] = (uint32_t)la | ((uint32_t)lb << 16);
        }
    }
    __syncthreads();                  // #1 xs visible

    // ---- phase 1: GEMM (bf16 3-pass); wave wv -> capsule wv; waves 0,1 also 8,9
    f32x4 acc1[3] = {}, acc2[3] = {};
    for (int kt = 0; kt < 8; ++kt) {
        int woff = (wv * 16 + row) * 256 + kt * 32 + g * 8;
        bf16x8 bh1 = *(const bf16x8*)(g_whi + woff);
        bf16x8 bl1 = *(const bf16x8*)(g_wlo + woff);
        bf16x8 bh2 = bh1, bl2 = bl1;
        if (dual) {
            int woff2 = (kB * 16 + row) * 256 + kt * 32 + g * 8;
            bh2 = *(const bf16x8*)(g_whi + woff2);
            bl2 = *(const bf16x8*)(g_wlo + woff2);
        }
        #pragma unroll
        for (int nt = 0; nt < 3; ++nt) {
            int o2 = (nt * 16 + row) * 264 + kt * 32 + g * 8;
            bf16x8 ah = *(const bf16x8*)(xshS + o2);
            bf16x8 al = *(const bf16x8*)(xslS + o2);
            acc1[nt] = mfma16(ah, bh1, acc1[nt]);
            acc1[nt] = mfma16(al, bh1, acc1[nt]);
            acc1[nt] = mfma16(ah, bl1, acc1[nt]);
            if (dual) {
                acc2[nt] = mfma16(ah, bh2, acc2[nt]);
                acc2[nt] = mfma16(al, bh2, acc2[nt]);
                acc2[nt] = mfma16(ah, bl2, acc2[nt]);
            }
        }
    }
    __syncthreads();                  // #2 xs reads done -> caps/u89/b/c may overlay

    // ---- C-write: caps[k][o*36+hw]
    {
        float bias1 = conv_b[wv * 16 + row];
        float bias2 = dual ? conv_b[kB * 16 + row] : 0.f;
        #pragma unroll
        for (int nt = 0; nt < 3; ++nt) {
            #pragma unroll
            for (int r = 0; r < 4; ++r) {
                int hw = nt * 16 + g * 4 + r;
                if (hw < HWSZ) {
                    caps_s[wv * 576 + row * HWSZ + hw] = acc1[nt][r] + bias1;
                    if (dual) caps_s[kB * 576 + row * HWSZ + hw] = acc2[nt][r] + bias2;
                }
            }
        }
    }
    __syncthreads();                  // #3 caps visible (u89 phase reads caps 8,9)

    // ---- phase 2a: own-capsule u in registers; lane (pr,e) holds u[wv][4*p4+pr][e]
    float u1r[18];
    float part1 = 0.f;
    #pragma unroll
    for (int p4 = 0; p4 < 18; ++p4) {
        int p = 4 * p4 + pr;
        const float4* cp4 = (const float4*)(caps_s + wv * 576 + p * 8);
        float4 c0 = cp4[0], c1 = cp4[1];
        const float4* wq = (const float4*)(g_wtsT + ((size_t)(wv * PRIM + p) * 16 + e) * 8);
        float4 w0 = wq[0], w1 = wq[1];
        float a = c0.x * w0.x;
        a = fmaf(c0.y, w0.y, a); a = fmaf(c0.z, w0.z, a); a = fmaf(c0.w, w0.w, a);
        a = fmaf(c1.x, w1.x, a); a = fmaf(c1.y, w1.y, a);
        a = fmaf(c1.z, w1.z, a); a = fmaf(c1.w, w1.w, a);
        u1r[p4] = a;
        part1 += a;
    }

    // ---- phase 2b: u for capsules 8,9 -> LDS, distributed over all 512 threads.
    //      task = (kx*72+p)*4 + e4 : u89[kx][p][e4*4..+3] = sum_d caps*wts (orig layout)
    for (int task = t; task < 576; task += 512) {
        int e4 = task & 3;
        int kp = task >> 2;           // 0..143
        int kx = kp / PRIM;
        int p  = kp - kx * PRIM;
        const float* cpp = caps_s + (8 + kx) * 576 + p * 8;
        const float4* w4 = (const float4*)(wts + (size_t)(((8 + kx) * PRIM + p) * PD) * EDIM) + e4;
        float4 a = {0.f, 0.f, 0.f, 0.f};
        #pragma unroll
        for (int d = 0; d < PD; ++d) {
            float cv = cpp[d];
            float4 wv4 = w4[d * 4];
            a.x = fmaf(cv, wv4.x, a.x);
            a.y = fmaf(cv, wv4.y, a.y);
            a.z = fmaf(cv, wv4.z, a.z);
            a.w = fmaf(cv, wv4.w, a.w);
        }
        *(float4*)(u89 + (kx * PRIM + p) * 16 + e4 * 4) = a;
    }
    __syncthreads();                  // #4 u89 visible

    // ---- routing iter 1: b=0 -> c=0.1 exactly
    float v1, v2 = 0.f;
    {
        float s1 = part1 + __shfl_xor(part1, 16);
        s1 += __shfl_xor(s1, 32);
        s1 *= 0.1f;
        float q1 = s1 * s1;
        q1 += __shfl_xor(q1, 1); q1 += __shfl_xor(q1, 2);
        q1 += __shfl_xor(q1, 4); q1 += __shfl_xor(q1, 8);
        v1 = s1 * (q1 / (1.f + q1)) * rsqrtf(q1 + 1e-8f);
        if (dual) {
            float p2 = 0.f;
            #pragma unroll
            for (int p4 = 0; p4 < 18; ++p4)
                p2 += u89[(wv * PRIM + 4 * p4 + pr) * 16 + e];
            float s2 = p2 + __shfl_xor(p2, 16);
            s2 += __shfl_xor(s2, 32);
            s2 *= 0.1f;
            float q2 = s2 * s2;
            q2 += __shfl_xor(q2, 1); q2 += __shfl_xor(q2, 2);
            q2 += __shfl_xor(q2, 4); q2 += __shfl_xor(q2, 8);
            v2 = s2 * (q2 / (1.f + q2)) * rsqrtf(q2 + 1e-8f);
        }
        #pragma unroll
        for (int p4 = 0; p4 < 18; ++p4) {
            float d1 = u1r[p4] * v1;
            d1 += __shfl_xor(d1, 1); d1 += __shfl_xor(d1, 2);
            d1 += __shfl_xor(d1, 4); d1 += __shfl_xor(d1, 8);
            if (e == 0) b_s[wv * PRIM + 4 * p4 + pr] = d1;
            if (dual) {
                float d2 = u89[(wv * PRIM + 4 * p4 + pr) * 16 + e] * v2;
                d2 += __shfl_xor(d2, 1); d2 += __shfl_xor(d2, 2);
                d2 += __shfl_xor(d2, 4); d2 += __shfl_xor(d2, 8);
                if (e == 0) b_s[kB * PRIM + 4 * p4 + pr] = d2;
            }
        }
    }

    // ---- routing iters 2,3
    #pragma unroll
    for (int it = 1; it < 3; ++it) {
        __syncthreads();              // b_s writes visible
        if (t < PRIM) {               // softmax over k per primary
            float bv[KCAPS];
            float m = -1e30f;
            #pragma unroll
            for (int k2 = 0; k2 < KCAPS; ++k2) { bv[k2] = b_s[k2 * PRIM + t]; m = fmaxf(m, bv[k2]); }
            float sum = 0.f;
            #pragma unroll
            for (int k2 = 0; k2 < KCAPS; ++k2) { bv[k2] = __expf(bv[k2] - m); sum += bv[k2]; }
            float inv = 1.f / sum;
            #pragma unroll
            for (int k2 = 0; k2 < KCAPS; ++k2) c_s[k2 * PRIM + t] = bv[k2] * inv;
        }
        __syncthreads();              // c_s visible
        float pa = 0.f, pb = 0.f;
        #pragma unroll
        for (int p4 = 0; p4 < 18; ++p4) {
            int p = 4 * p4 + pr;
            pa = fmaf(c_s[wv * PRIM + p], u1r[p4], pa);
            if (dual) pb = fmaf(c_s[kB * PRIM + p], u89[(wv * PRIM + p) * 16 + e], pb);
        }
        float s1 = pa + __shfl_xor(pa, 16);
        s1 += __shfl_xor(s1, 32);
        float q1 = s1 * s1;
        q1 += __shfl_xor(q1, 1); q1 += __shfl_xor(q1, 2);
        q1 += __shfl_xor(q1, 4); q1 += __shfl_xor(q1, 8);
        v1 = s1 * (q1 / (1.f + q1)) * rsqrtf(q1 + 1e-8f);
        if (dual) {
            float s2 = pb + __shfl_xor(pb, 16);
            s2 += __shfl_xor(s2, 32);
            float q2 = s2 * s2;
            q2 += __shfl_xor(q2, 1); q2 += __shfl_xor(q2, 2);
            q2 += __shfl_xor(q2, 4); q2 += __shfl_xor(q2, 8);
            v2 = s2 * (q2 / (1.f + q2)) * rsqrtf(q2 + 1e-8f);
        }
        if (it < 2) {                 // agreement update (skip after final iter)
            #pragma unroll
            for (int p4 = 0; p4 < 18; ++p4) {
                float d1 = u1r[p4] * v1;
                d1 += __shfl_xor(d1, 1); d1 += __shfl_xor(d1, 2);
                d1 += __shfl_xor(d1, 4); d1 += __shfl_xor(d1, 8);
                if (e == 0) b_s[wv * PRIM + 4 * p4 + pr] += d1;
                if (dual) {
                    float d2 = u89[(wv * PRIM + 4 * p4 + pr) * 16 + e] * v2;
                    d2 += __shfl_xor(d2, 1); d2 += __shfl_xor(d2, 2);
                    d2 += __shfl_xor(d2, 4); d2 += __shfl_xor(d2, 8);
                    if (e == 0) b_s[kB * PRIM + 4 * p4 + pr] += d2;
                }
            }
        }
    }

    if (ln < 16) {
        out[(size_t)bb * (KCAPS * EDIM) + wv * 16 + ln] = v1;
        if (dual) out[(size_t)bb * (KCAPS * EDIM) + kB * 16 + ln] = v2;
    }
}

extern "C" void kernel_launch(void* const* d_in, const int* in_sizes, int n_in,
                              void* d_out, int out_size, void* d_ws, size_t ws_size,
                              hipStream_t stream) {
    const float* x  = (const float*)d_in[0];
    const float* cw = (const float*)d_in[1];
    const float* cb = (const float*)d_in[2];
    const float* wt = (const float*)d_in[3];
    float* out = (float*)d_out;
    const int B = in_sizes[0] / (IC * HWSZ);   // 2048

    hipLaunchKernelGGL(prep_kernel, dim3((KCAPS * PRIM * EDIM * PD + 255) / 256), dim3(256),
                       0, stream, cw, wt);

    hipFuncSetAttribute(reinterpret_cast<const void*>(&caps_512),
                        hipFuncAttributeMaxDynamicSharedMemorySize, SMEM_BYTES);
    hipLaunchKernelGGL(caps_512, dim3(B), dim3(512), SMEM_BYTES, stream, x, cb, wt, out);
}

// Round 10
// 441.863 us; speedup vs baseline: 1.3849x; 1.3849x over previous
//
#include <hip/hip_runtime.h>
#include <stdint.h>

#define KCAPS 10
#define OC    16
#define IC    256
#define HWSZ  36
#define PRIM  72
#define PD    8
#define EDIM  16

typedef short bf16x8 __attribute__((ext_vector_type(8)));
typedef float f32x4  __attribute__((ext_vector_type(4)));

// persistent prepped weights (recomputed every launch -> deterministic)
__device__ unsigned short g_whi[KCAPS * OC * IC];
__device__ unsigned short g_wlo[KCAPS * OC * IC];
__device__ float          g_wtsT[KCAPS * PRIM * EDIM * PD];   // [k][p][e][d]

// LDS map (44352 B):
//   [0, 19008)      xsh u32[36][132]  (bf16 [36][264])
//   [19008, 38016)  xsl u32[36][132]
//   [38016, 44352)  slack: GEMM A-fragment reads for discarded D-rows 36..47
//                   over-run xsl (garbage, in-bounds, results discarded)
//   post-GEMM overlay (xs dead after barrier #2):
//   f32 [0, 5760)       caps [10][576]
//   f32 [5760, 8064)    u89  [2][72][16]
//   f32 [8064, 8784)    b_s  [720]
//   f32 [8784, 9504)    c_s  [720]
#define SMEM_BYTES 44352

__device__ __forceinline__ void bf_split(float v, unsigned short& hb, unsigned short& lb) {
    __bf16 h = (__bf16)v;
    hb = __builtin_bit_cast(unsigned short, h);
    __bf16 l = (__bf16)(v - (float)h);
    lb = __builtin_bit_cast(unsigned short, l);
}

__device__ __forceinline__ f32x4 mfma16(bf16x8 a, bf16x8 b, f32x4 c) {
    return __builtin_amdgcn_mfma_f32_16x16x32_bf16(a, b, c, 0, 0, 0);
}

__global__ __launch_bounds__(256)
void prep_kernel(const float* __restrict__ w, const float* __restrict__ wts) {
    int i = blockIdx.x * 256 + threadIdx.x;
    if (i < KCAPS * OC * IC) {
        unsigned short hb, lb;
        bf_split(w[i], hb, lb);
        g_whi[i] = hb;
        g_wlo[i] = lb;
    }
    if (i < KCAPS * PRIM * EDIM * PD) {           // 92160: [kp][e][d] <- [kp][d][e]
        int d = i & 7, e = (i >> 3) & 15, kp = i >> 7;
        g_wtsT[i] = wts[(size_t)kp * 128 + d * 16 + e];
    }
}

// (512,4): register budget 128 total (VGPR+AGPR unified). R8/R9's (512,6) was
// rounded up to the 8-waves/EU step (64 total) by the compiler -> 40 arch regs
// -> u1r spilled to scratch (1.1+ GB WRITE_SIZE). Expected here: ~60 arch + 24
// acc ~= 84 total -> floor(512/84)=6 waves/EU -> 3 blocks/CU (LDS allows 3.6).
__global__ __launch_bounds__(512, 4)
void caps_512(const float* __restrict__ x, const float* __restrict__ conv_b,
              const float* __restrict__ wts, float* __restrict__ out) {
    extern __shared__ char smem[];
    uint32_t* xsh = (uint32_t*)smem;              // [36][132]
    uint32_t* xsl = xsh + 36 * 132;               // [36][132] (+slack beyond)
    const short* xshS = (const short*)xsh;
    const short* xslS = (const short*)xsl;
    float* sm_f   = (float*)smem;
    float* caps_s = sm_f;                         // [10][576]
    float* u89    = sm_f + 5760;                  // [2][72][16]
    float* b_s    = sm_f + 8064;                  // [720]
    float* c_s    = sm_f + 8784;                  // [720]

    const int t  = threadIdx.x;
    const int bb = blockIdx.x;
    const int wv = t >> 6;            // wave 0..7 owns capsule wv; waves 0,1 also 8,9
    const int ln = t & 63;
    const int row = ln & 15;          // GEMM: tile row | routing: e
    const int g   = ln >> 4;          // GEMM: k-group  | routing: pr
    const int e   = row;
    const int pr  = g;
    const bool dual = (wv < 2);
    const int kB = 8 + wv;

    // ---- phase 0: stage x transposed -> bf16 hi/lo [36 hw][264 c]
    {
        const float4* x4 = (const float4*)(x + (size_t)bb * (IC * HWSZ));
        for (int task = t; task < 1152; task += 512) {   // 128 c-pairs x 9 hw-quads
            int cp = task / 9, hq = task - cp * 9;
            float4 va = x4[(2 * cp) * 9 + hq];
            float4 vb = x4[(2 * cp + 1) * 9 + hq];
            int base = (4 * hq) * 132 + cp;
            unsigned short ha, la, hb, lb;
            bf_split(va.x, ha, la); bf_split(vb.x, hb, lb);
            xsh[base]       = (uint32_t)ha | ((uint32_t)hb << 16);
            xsl[base]       = (uint32_t)la | ((uint32_t)lb << 16);
            bf_split(va.y, ha, la); bf_split(vb.y, hb, lb);
            xsh[base + 132] = (uint32_t)ha | ((uint32_t)hb << 16);
            xsl[base + 132] = (uint32_t)la | ((uint32_t)lb << 16);
            bf_split(va.z, ha, la); bf_split(vb.z, hb, lb);
            xsh[base + 264] = (uint32_t)ha | ((uint32_t)hb << 16);
            xsl[base + 264] = (uint32_t)la | ((uint32_t)lb << 16);
            bf_split(va.w, ha, la); bf_split(vb.w, hb, lb);
            xsh[base + 396] = (uint32_t)ha | ((uint32_t)hb << 16);
            xsl[base + 396] = (uint32_t)la | ((uint32_t)lb << 16);
        }
    }
    __syncthreads();                  // #1 xs visible

    // ---- phase 1: GEMM (bf16 3-pass); wave wv -> capsule wv; waves 0,1 also 8,9
    f32x4 acc1[3] = {}, acc2[3] = {};
    for (int kt = 0; kt < 8; ++kt) {
        int woff = (wv * 16 + row) * 256 + kt * 32 + g * 8;
        bf16x8 bh1 = *(const bf16x8*)(g_whi + woff);
        bf16x8 bl1 = *(const bf16x8*)(g_wlo + woff);
        bf16x8 bh2 = bh1, bl2 = bl1;
        if (dual) {
            int woff2 = (kB * 16 + row) * 256 + kt * 32 + g * 8;
            bh2 = *(const bf16x8*)(g_whi + woff2);
            bl2 = *(const bf16x8*)(g_wlo + woff2);
        }
        #pragma unroll
        for (int nt = 0; nt < 3; ++nt) {
            int o2 = (nt * 16 + row) * 264 + kt * 32 + g * 8;
            bf16x8 ah = *(const bf16x8*)(xshS + o2);
            bf16x8 al = *(const bf16x8*)(xslS + o2);
            acc1[nt] = mfma16(ah, bh1, acc1[nt]);
            acc1[nt] = mfma16(al, bh1, acc1[nt]);
            acc1[nt] = mfma16(ah, bl1, acc1[nt]);
            if (dual) {
                acc2[nt] = mfma16(ah, bh2, acc2[nt]);
                acc2[nt] = mfma16(al, bh2, acc2[nt]);
                acc2[nt] = mfma16(ah, bl2, acc2[nt]);
            }
        }
    }
    __syncthreads();                  // #2 xs reads done -> caps/u89/b/c may overlay

    // ---- C-write: caps[k][o*36+hw]
    {
        float bias1 = conv_b[wv * 16 + row];
        float bias2 = dual ? conv_b[kB * 16 + row] : 0.f;
        #pragma unroll
        for (int nt = 0; nt < 3; ++nt) {
            #pragma unroll
            for (int r = 0; r < 4; ++r) {
                int hw = nt * 16 + g * 4 + r;
                if (hw < HWSZ) {
                    caps_s[wv * 576 + row * HWSZ + hw] = acc1[nt][r] + bias1;
                    if (dual) caps_s[kB * 576 + row * HWSZ + hw] = acc2[nt][r] + bias2;
                }
            }
        }
    }
    __syncthreads();                  // #3 caps visible (u89 phase reads caps 8,9)

    // ---- phase 2a: own-capsule u in registers; lane (pr,e) holds u[wv][4*p4+pr][e]
    float u1r[18];
    float part1 = 0.f;
    #pragma unroll
    for (int p4 = 0; p4 < 18; ++p4) {
        int p = 4 * p4 + pr;
        const float4* cp4 = (const float4*)(caps_s + wv * 576 + p * 8);
        float4 c0 = cp4[0], c1 = cp4[1];
        const float4* wq = (const float4*)(g_wtsT + ((size_t)(wv * PRIM + p) * 16 + e) * 8);
        float4 w0 = wq[0], w1 = wq[1];
        float a = c0.x * w0.x;
        a = fmaf(c0.y, w0.y, a); a = fmaf(c0.z, w0.z, a); a = fmaf(c0.w, w0.w, a);
        a = fmaf(c1.x, w1.x, a); a = fmaf(c1.y, w1.y, a);
        a = fmaf(c1.z, w1.z, a); a = fmaf(c1.w, w1.w, a);
        u1r[p4] = a;
        part1 += a;
    }

    // ---- phase 2b: u for capsules 8,9 -> LDS, distributed over all 512 threads.
    //      task = (kx*72+p)*4 + e4 : u89[kx][p][e4*4..+3] = sum_d caps*wts (orig layout)
    for (int task = t; task < 576; task += 512) {
        int e4 = task & 3;
        int kp = task >> 2;           // 0..143
        int kx = kp / PRIM;
        int p  = kp - kx * PRIM;
        const float* cpp = caps_s + (8 + kx) * 576 + p * 8;
        const float4* w4 = (const float4*)(wts + (size_t)(((8 + kx) * PRIM + p) * PD) * EDIM) + e4;
        float4 a = {0.f, 0.f, 0.f, 0.f};
        #pragma unroll
        for (int d = 0; d < PD; ++d) {
            float cv = cpp[d];
            float4 wv4 = w4[d * 4];
            a.x = fmaf(cv, wv4.x, a.x);
            a.y = fmaf(cv, wv4.y, a.y);
            a.z = fmaf(cv, wv4.z, a.z);
            a.w = fmaf(cv, wv4.w, a.w);
        }
        *(float4*)(u89 + (kx * PRIM + p) * 16 + e4 * 4) = a;
    }
    __syncthreads();                  // #4 u89 visible

    // ---- routing iter 1: b=0 -> c=0.1 exactly
    float v1, v2 = 0.f;
    {
        float s1 = part1 + __shfl_xor(part1, 16);
        s1 += __shfl_xor(s1, 32);
        s1 *= 0.1f;
        float q1 = s1 * s1;
        q1 += __shfl_xor(q1, 1); q1 += __shfl_xor(q1, 2);
        q1 += __shfl_xor(q1, 4); q1 += __shfl_xor(q1, 8);
        v1 = s1 * (q1 / (1.f + q1)) * rsqrtf(q1 + 1e-8f);
        if (dual) {
            float p2 = 0.f;
            #pragma unroll
            for (int p4 = 0; p4 < 18; ++p4)
                p2 += u89[(wv * PRIM + 4 * p4 + pr) * 16 + e];
            float s2 = p2 + __shfl_xor(p2, 16);
            s2 += __shfl_xor(s2, 32);
            s2 *= 0.1f;
            float q2 = s2 * s2;
            q2 += __shfl_xor(q2, 1); q2 += __shfl_xor(q2, 2);
            q2 += __shfl_xor(q2, 4); q2 += __shfl_xor(q2, 8);
            v2 = s2 * (q2 / (1.f + q2)) * rsqrtf(q2 + 1e-8f);
        }
        #pragma unroll
        for (int p4 = 0; p4 < 18; ++p4) {
            float d1 = u1r[p4] * v1;
            d1 += __shfl_xor(d1, 1); d1 += __shfl_xor(d1, 2);
            d1 += __shfl_xor(d1, 4); d1 += __shfl_xor(d1, 8);
            if (e == 0) b_s[wv * PRIM + 4 * p4 + pr] = d1;
            if (dual) {
                float d2 = u89[(wv * PRIM + 4 * p4 + pr) * 16 + e] * v2;
                d2 += __shfl_xor(d2, 1); d2 += __shfl_xor(d2, 2);
                d2 += __shfl_xor(d2, 4); d2 += __shfl_xor(d2, 8);
                if (e == 0) b_s[kB * PRIM + 4 * p4 + pr] = d2;
            }
        }
    }

    // ---- routing iters 2,3
    #pragma unroll
    for (int it = 1; it < 3; ++it) {
        __syncthreads();              // b_s writes visible
        if (t < PRIM) {               // softmax over k per primary
            float bv[KCAPS];
            float m = -1e30f;
            #pragma unroll
            for (int k2 = 0; k2 < KCAPS; ++k2) { bv[k2] = b_s[k2 * PRIM + t]; m = fmaxf(m, bv[k2]); }
            float sum = 0.f;
            #pragma unroll
            for (int k2 = 0; k2 < KCAPS; ++k2) { bv[k2] = __expf(bv[k2] - m); sum += bv[k2]; }
            float inv = 1.f / sum;
            #pragma unroll
            for (int k2 = 0; k2 < KCAPS; ++k2) c_s[k2 * PRIM + t] = bv[k2] * inv;
        }
        __syncthreads();              // c_s visible
        float pa = 0.f, pb = 0.f;
        #pragma unroll
        for (int p4 = 0; p4 < 18; ++p4) {
            int p = 4 * p4 + pr;
            pa = fmaf(c_s[wv * PRIM + p], u1r[p4], pa);
            if (dual) pb = fmaf(c_s[kB * PRIM + p], u89[(wv * PRIM + p) * 16 + e], pb);
        }
        float s1 = pa + __shfl_xor(pa, 16);
        s1 += __shfl_xor(s1, 32);
        float q1 = s1 * s1;
        q1 += __shfl_xor(q1, 1); q1 += __shfl_xor(q1, 2);
        q1 += __shfl_xor(q1, 4); q1 += __shfl_xor(q1, 8);
        v1 = s1 * (q1 / (1.f + q1)) * rsqrtf(q1 + 1e-8f);
        if (dual) {
            float s2 = pb + __shfl_xor(pb, 16);
            s2 += __shfl_xor(s2, 32);
            float q2 = s2 * s2;
            q2 += __shfl_xor(q2, 1); q2 += __shfl_xor(q2, 2);
            q2 += __shfl_xor(q2, 4); q2 += __shfl_xor(q2, 8);
            v2 = s2 * (q2 / (1.f + q2)) * rsqrtf(q2 + 1e-8f);
        }
        if (it < 2) {                 // agreement update (skip after final iter)
            #pragma unroll
            for (int p4 = 0; p4 < 18; ++p4) {
                float d1 = u1r[p4] * v1;
                d1 += __shfl_xor(d1, 1); d1 += __shfl_xor(d1, 2);
                d1 += __shfl_xor(d1, 4); d1 += __shfl_xor(d1, 8);
                if (e == 0) b_s[wv * PRIM + 4 * p4 + pr] += d1;
                if (dual) {
                    float d2 = u89[(wv * PRIM + 4 * p4 + pr) * 16 + e] * v2;
                    d2 += __shfl_xor(d2, 1); d2 += __shfl_xor(d2, 2);
                    d2 += __shfl_xor(d2, 4); d2 += __shfl_xor(d2, 8);
                    if (e == 0) b_s[kB * PRIM + 4 * p4 + pr] += d2;
                }
            }
        }
    }

    if (ln < 16) {
        out[(size_t)bb * (KCAPS * EDIM) + wv * 16 + ln] = v1;
        if (dual) out[(size_t)bb * (KCAPS * EDIM) + kB * 16 + ln] = v2;
    }
}

extern "C" void kernel_launch(void* const* d_in, const int* in_sizes, int n_in,
                              void* d_out, int out_size, void* d_ws, size_t ws_size,
                              hipStream_t stream) {
    const float* x  = (const float*)d_in[0];
    const float* cw = (const float*)d_in[1];
    const float* cb = (const float*)d_in[2];
    const float* wt = (const float*)d_in[3];
    float* out = (float*)d_out;
    const int B = in_sizes[0] / (IC * HWSZ);   // 2048

    hipLaunchKernelGGL(prep_kernel, dim3((KCAPS * PRIM * EDIM * PD + 255) / 256), dim3(256),
                       0, stream, cw, wt);

    hipFuncSetAttribute(reinterpret_cast<const void*>(&caps_512),
                        hipFuncAttributeMaxDynamicSharedMemorySize, SMEM_BYTES);
    hipLaunchKernelGGL(caps_512, dim3(B), dim3(512), SMEM_BYTES, stream, x, cb, wt, out);
}

// Round 11
// 107.870 us; speedup vs baseline: 5.6728x; 4.0963x over previous
//
#include <hip/hip_runtime.h>
#include <stdint.h>

#define KCAPS 10
#define OC    16
#define IC    256
#define HWSZ  36
#define PRIM  72
#define PD    8
#define EDIM  16
#define BMAX  2048

typedef short bf16x8 __attribute__((ext_vector_type(8)));
typedef float f32x4  __attribute__((ext_vector_type(4)));

// persistent prepped weights (recomputed every launch -> deterministic)
__device__ unsigned short g_whi[KCAPS * OC * IC];
__device__ unsigned short g_wlo[KCAPS * OC * IC];
__device__ float4         g_wtsT4[KCAPS * PD * 4 * PRIM];   // [k][(d*4+e4)][p] -> wts[k,p,d,e4*4..3]
__device__ float          g_caps_fallback[(size_t)BMAX * 160 * HWSZ];

// ---------------- kernel A LDS (44352 B): xs only ----------------
//   [0, 19008)      xsh u32[36][132]  (bf16 [36][264])
//   [19008, 38016)  xsl u32[36][132]
//   [38016, 44352)  slack for A-fragment garbage reads of D-rows 36..47
#define SMEM_A 44352

// ---------------- kernel B LDS (52776 B) ----------------
//   f32 [0, 11584)      u_t [16][724]
//   f32 [11584, 12304)  b_s [720]
//   f32 [12304, 13024)  c_s [720]
//   f32 [13024, 13184)  v_s [160]
//   f32 [13184, 13194)  scale_s [10]
#define SMEM_B (13194 * 4)

__device__ __forceinline__ void bf_split(float v, unsigned short& hb, unsigned short& lb) {
    __bf16 h = (__bf16)v;
    hb = __builtin_bit_cast(unsigned short, h);
    __bf16 l = (__bf16)(v - (float)h);
    lb = __builtin_bit_cast(unsigned short, l);
}

__device__ __forceinline__ f32x4 mfma16(bf16x8 a, bf16x8 b, f32x4 c) {
    return __builtin_amdgcn_mfma_f32_16x16x32_bf16(a, b, c, 0, 0, 0);
}

__global__ __launch_bounds__(256)
void prep_kernel(const float* __restrict__ w, const float* __restrict__ wts) {
    int i = blockIdx.x * 256 + threadIdx.x;
    if (i < KCAPS * OC * IC) {                 // 40960
        unsigned short hb, lb;
        bf_split(w[i], hb, lb);
        g_whi[i] = hb;
        g_wlo[i] = lb;
    }
    if (i < KCAPS * PD * 4 * PRIM) {           // 23040 float4 tasks
        int p = i % PRIM;
        int r = i / PRIM;
        int e4 = r & 3;
        int d  = (r >> 2) & 7;
        int k  = r >> 5;
        g_wtsT4[i] = *(const float4*)(wts + (size_t)(((k * PRIM + p) * PD + d) * EDIM + e4 * 4));
    }
}

// ---- kernel A: per-batch-element conv GEMM (bf16 3-pass), caps -> global f32
__global__ __launch_bounds__(256, 2)
void gemm_caps(const float* __restrict__ x, const float* __restrict__ conv_b,
               float* __restrict__ caps_g) {
    extern __shared__ char smem[];
    uint32_t* xsh = (uint32_t*)smem;            // [36][132]
    uint32_t* xsl = xsh + 36 * 132;             // [36][132] (+slack beyond)
    const short* xshS = (const short*)xsh;
    const short* xslS = (const short*)xsl;

    const int t  = threadIdx.x;
    const int bb = blockIdx.x;
    const int wv = t >> 6;            // 4 waves; wave wv -> m-tiles {wv, wv+4[, wv+8]}
    const int ln = t & 63;
    const int row = ln & 15;
    const int g   = ln >> 4;
    const int nm  = (wv < 2) ? 3 : 2;

    // stage x transposed -> bf16 hi/lo [36 hw][264 c]
    {
        const float4* x4 = (const float4*)(x + (size_t)bb * (IC * HWSZ));
        for (int task = t; task < 1152; task += 256) {   // 128 c-pairs x 9 hw-quads
            int cp = task / 9, hq = task - cp * 9;
            float4 va = x4[(2 * cp) * 9 + hq];
            float4 vb = x4[(2 * cp + 1) * 9 + hq];
            int base = (4 * hq) * 132 + cp;
            unsigned short ha, la, hb, lb;
            bf_split(va.x, ha, la); bf_split(vb.x, hb, lb);
            xsh[base]       = (uint32_t)ha | ((uint32_t)hb << 16);
            xsl[base]       = (uint32_t)la | ((uint32_t)lb << 16);
            bf_split(va.y, ha, la); bf_split(vb.y, hb, lb);
            xsh[base + 132] = (uint32_t)ha | ((uint32_t)hb << 16);
            xsl[base + 132] = (uint32_t)la | ((uint32_t)lb << 16);
            bf_split(va.z, ha, la); bf_split(vb.z, hb, lb);
            xsh[base + 264] = (uint32_t)ha | ((uint32_t)hb << 16);
            xsl[base + 264] = (uint32_t)la | ((uint32_t)lb << 16);
            bf_split(va.w, ha, la); bf_split(vb.w, hb, lb);
            xsh[base + 396] = (uint32_t)ha | ((uint32_t)hb << 16);
            xsl[base + 396] = (uint32_t)la | ((uint32_t)lb << 16);
        }
    }
    __syncthreads();

    // GEMM: acc[mi][nt], m-tile mt = wv + 4*mi, D-col m = mt*16+row, D-row hw = nt*16+g*4+r
    f32x4 acc[3][3] = {};
    for (int kt = 0; kt < 8; ++kt) {
        bf16x8 bh[3], bl[3];
        #pragma unroll
        for (int mi = 0; mi < 3; ++mi) {
            if (mi < nm) {
                int woff = ((wv + 4 * mi) * 16 + row) * 256 + kt * 32 + g * 8;
                bh[mi] = *(const bf16x8*)(g_whi + woff);
                bl[mi] = *(const bf16x8*)(g_wlo + woff);
            }
        }
        bf16x8 ah[3], al[3];
        #pragma unroll
        for (int nt = 0; nt < 3; ++nt) {
            int o2 = (nt * 16 + row) * 264 + kt * 32 + g * 8;
            ah[nt] = *(const bf16x8*)(xshS + o2);
            al[nt] = *(const bf16x8*)(xslS + o2);
        }
        #pragma unroll
        for (int mi = 0; mi < 3; ++mi) {
            if (mi < nm) {
                #pragma unroll
                for (int nt = 0; nt < 3; ++nt) {
                    acc[mi][nt] = mfma16(ah[nt], bh[mi], acc[mi][nt]);
                    acc[mi][nt] = mfma16(al[nt], bh[mi], acc[mi][nt]);
                    acc[mi][nt] = mfma16(ah[nt], bl[mi], acc[mi][nt]);
                }
            }
        }
    }

    // write caps[b][m][hw] f32 (+bias), float4 per (mi,nt) where hw0 < 36
    float* cg = caps_g + (size_t)bb * (160 * HWSZ);
    #pragma unroll
    for (int mi = 0; mi < 3; ++mi) {
        if (mi < nm) {
            int m = (wv + 4 * mi) * 16 + row;
            float bias = conv_b[m];
            #pragma unroll
            for (int nt = 0; nt < 3; ++nt) {
                int hw0 = nt * 16 + g * 4;
                if (hw0 < HWSZ) {
                    float4 o;
                    o.x = acc[mi][nt][0] + bias;
                    o.y = acc[mi][nt][1] + bias;
                    o.z = acc[mi][nt][2] + bias;
                    o.w = acc[mi][nt][3] + bias;
                    *(float4*)(cg + m * HWSZ + hw0) = o;
                }
            }
        }
    }
}

// ---- kernel B: u-transform + dynamic routing per batch element
__global__ __launch_bounds__(256, 2)
void route_kernel(const float* __restrict__ caps_g, float* __restrict__ out) {
    extern __shared__ char smem[];
    float* u_t     = (float*)smem;            // [16][724]
    float* b_s     = u_t + 16 * 724;          // [720]
    float* c_s     = b_s + 720;               // [720]
    float* v_s     = c_s + 720;               // [160]
    float* scale_s = v_s + 160;               // [10]

    const int t  = threadIdx.x;
    const int bb = blockIdx.x;

    // u-transform: task = k*72+p; thread computes u[task][0..15], stores transposed
    {
        const float4* cg4 = (const float4*)(caps_g + (size_t)bb * (160 * HWSZ));
        for (int task = t; task < KCAPS * PRIM; task += 256) {
            int k = task / PRIM;
            int p = task - k * PRIM;
            float4 c0 = cg4[task * 2];        // caps[k*576 + p*8 .. +7]
            float4 c1 = cg4[task * 2 + 1];
            float pv[PD] = {c0.x, c0.y, c0.z, c0.w, c1.x, c1.y, c1.z, c1.w};
            const float4* wb = g_wtsT4 + k * (PD * 4 * PRIM) + p;
            float au[EDIM] = {};
            #pragma unroll
            for (int d = 0; d < PD; ++d) {
                #pragma unroll
                for (int e4 = 0; e4 < 4; ++e4) {
                    float4 w4 = wb[(d * 4 + e4) * PRIM];
                    au[e4 * 4 + 0] = fmaf(pv[d], w4.x, au[e4 * 4 + 0]);
                    au[e4 * 4 + 1] = fmaf(pv[d], w4.y, au[e4 * 4 + 1]);
                    au[e4 * 4 + 2] = fmaf(pv[d], w4.z, au[e4 * 4 + 2]);
                    au[e4 * 4 + 3] = fmaf(pv[d], w4.w, au[e4 * 4 + 3]);
                }
            }
            #pragma unroll
            for (int e = 0; e < EDIM; ++e) u_t[e * 724 + task] = au[e];
        }
    }
    for (int i = t; i < KCAPS * PRIM; i += 256) b_s[i] = 0.f;
    __syncthreads();

    // routing, 3 iterations (R3-verified structure)
    for (int it = 0; it < 3; ++it) {
        if (t < PRIM) {                  // softmax over k per primary p = t
            float bv[KCAPS];
            float m = -1e30f;
            #pragma unroll
            for (int k2 = 0; k2 < KCAPS; ++k2) { bv[k2] = b_s[k2 * PRIM + t]; m = fmaxf(m, bv[k2]); }
            float sum = 0.f;
            #pragma unroll
            for (int k2 = 0; k2 < KCAPS; ++k2) { bv[k2] = __expf(bv[k2] - m); sum += bv[k2]; }
            float inv = 1.f / sum;
            #pragma unroll
            for (int k2 = 0; k2 < KCAPS; ++k2) c_s[k2 * PRIM + t] = bv[k2] * inv;
        }
        __syncthreads();

        if (t < KCAPS * EDIM) {          // s[k][e] = sum_p c*u
            int k = t >> 4, e = t & 15;
            float s = 0.f;
            const float* ur = u_t + e * 724 + k * PRIM;
            const float* cr = c_s + k * PRIM;
            for (int p = 0; p < PRIM; ++p) s = fmaf(cr[p], ur[p], s);
            v_s[t] = s;
        }
        __syncthreads();

        if (t < KCAPS) {                 // squash scale
            float sq = 0.f;
            #pragma unroll
            for (int e = 0; e < EDIM; ++e) { float sv = v_s[t * EDIM + e]; sq = fmaf(sv, sv, sq); }
            scale_s[t] = (sq / (1.f + sq)) * rsqrtf(sq + 1e-8f);
        }
        __syncthreads();

        if (t < KCAPS * EDIM) v_s[t] *= scale_s[t >> 4];
        __syncthreads();

        if (it < 2) {                    // agreement update
            for (int task = t; task < KCAPS * PRIM; task += 256) {
                int k = task / PRIM;
                float dot = 0.f;
                const float* vr = v_s + k * EDIM;
                #pragma unroll
                for (int e = 0; e < EDIM; ++e) dot = fmaf(u_t[e * 724 + task], vr[e], dot);
                b_s[task] += dot;
            }
            __syncthreads();
        }
    }

    if (t < KCAPS * EDIM) out[(size_t)bb * (KCAPS * EDIM) + t] = v_s[t];
}

extern "C" void kernel_launch(void* const* d_in, const int* in_sizes, int n_in,
                              void* d_out, int out_size, void* d_ws, size_t ws_size,
                              hipStream_t stream) {
    const float* x  = (const float*)d_in[0];
    const float* cw = (const float*)d_in[1];
    const float* cb = (const float*)d_in[2];
    const float* wt = (const float*)d_in[3];
    float* out = (float*)d_out;
    const int B = in_sizes[0] / (IC * HWSZ);   // 2048

    // caps workspace: prefer d_ws, fall back to device symbol
    size_t capsNeed = (size_t)B * 160 * HWSZ * sizeof(float);   // 47.2 MB
    float* caps_g = nullptr;
    if (d_ws != nullptr && ws_size >= capsNeed) {
        caps_g = (float*)d_ws;
    } else {
        void* sym = nullptr;
        hipGetSymbolAddress(&sym, HIP_SYMBOL(g_caps_fallback));
        caps_g = (float*)sym;
    }

    hipLaunchKernelGGL(prep_kernel, dim3(160), dim3(256), 0, stream, cw, wt);

    hipFuncSetAttribute(reinterpret_cast<const void*>(&gemm_caps),
                        hipFuncAttributeMaxDynamicSharedMemorySize, SMEM_A);
    hipLaunchKernelGGL(gemm_caps, dim3(B), dim3(256), SMEM_A, stream, x, cb, caps_g);

    hipFuncSetAttribute(reinterpret_cast<const void*>(&route_kernel),
                        hipFuncAttributeMaxDynamicSharedMemorySize, SMEM_B);
    hipLaunchKernelGGL(route_kernel, dim3(B), dim3(256), SMEM_B, stream, caps_g, out);
}